// Round 1
// baseline (97.174 us; speedup 1.0000x reference)
//
#include <hip/hip_runtime.h>

// Problem constants (fixed by the reference's setup_inputs()):
#define BATCH   8
#define TFRAMES 8
#define BT      (BATCH * TFRAMES)   // 64
#define NPTS    1024
#define NCH     32
#define WS      128
#define HW      (WS * WS)           // 16384
#define SPLIT   4                   // blocks per frame; 256 thr * 4 = 1024 segments

// ---------------------------------------------------------------------------
// Kernel 1: per-frame segment means scattered (atomically) into the dense
// accumulator grid living in d_out.
//   w_acc   : [B][C][HW]  (sum over T of per-frame segment means)
//   mask_acc: [B][HW]     (sum over T of per-cell counts)
// ---------------------------------------------------------------------------
__global__ __launch_bounds__(256) void seg_scatter_kernel(
    const float* __restrict__ w_part,        // [BT][NPTS][NCH]
    const int*   __restrict__ sorted_idx,    // [BT][NPTS]
    const int*   __restrict__ uniq_list,     // [BT][NPTS]
    const int*   __restrict__ uniq_cnt,      // [BT][NPTS]
    float*       __restrict__ w_acc,         // [B][C][HW]
    float*       __restrict__ mask_acc)      // [B][HW]
{
    __shared__ int s_cnt[NPTS];
    __shared__ int s_start[NPTS];
    __shared__ int s_tot[256];

    const int tid   = threadIdx.x;
    const int bt    = blockIdx.x / SPLIT;
    const int split = blockIdx.x % SPLIT;
    const int b     = bt / TFRAMES;

    // ---- load counts (int4, coalesced) & thread-local inclusive sums ----
    const int4* cp = reinterpret_cast<const int4*>(uniq_cnt + bt * NPTS);
    int4 c4 = cp[tid];
    s_cnt[tid * 4 + 0] = c4.x;
    s_cnt[tid * 4 + 1] = c4.y;
    s_cnt[tid * 4 + 2] = c4.z;
    s_cnt[tid * 4 + 3] = c4.w;
    const int l0 = c4.x;
    const int l1 = l0 + c4.y;
    const int l2 = l1 + c4.z;
    const int l3 = l2 + c4.w;
    s_tot[tid] = l3;
    __syncthreads();

    // ---- Hillis-Steele inclusive scan over the 256 thread totals ----
    for (int off = 1; off < 256; off <<= 1) {
        int v = (tid >= off) ? s_tot[tid - off] : 0;
        __syncthreads();
        s_tot[tid] += v;
        __syncthreads();
    }
    const int ex = (tid > 0) ? s_tot[tid - 1] : 0;
    s_start[tid * 4 + 0] = ex;
    s_start[tid * 4 + 1] = ex + l0;
    s_start[tid * 4 + 2] = ex + l1;
    s_start[tid * 4 + 3] = ex + l2;
    __syncthreads();

    // ---- each thread owns exactly one segment ----
    const int s = split * 256 + tid;
    const int cnt = s_cnt[s];
    if (cnt <= 0) return;                       // no barriers after this point
    const int start = s_start[s];
    const int cell  = uniq_list[bt * NPTS + s];

    float acc[NCH];
#pragma unroll
    for (int c = 0; c < NCH; ++c) acc[c] = 0.0f;

    const int* si = sorted_idx + bt * NPTS;
    for (int p = start; p < start + cnt; ++p) {
        const int j = si[p];
        const float4* wr =
            reinterpret_cast<const float4*>(w_part + ((size_t)bt * NPTS + j) * NCH);
        float4 v[8];
#pragma unroll
        for (int q = 0; q < 8; ++q) v[q] = wr[q];
        float ss = 0.0f;
#pragma unroll
        for (int q = 0; q < 8; ++q)
            ss += v[q].x * v[q].x + v[q].y * v[q].y + v[q].z * v[q].z + v[q].w * v[q].w;
        const float scale = 1.0f / fmaxf(sqrtf(ss), 1e-12f);
#pragma unroll
        for (int q = 0; q < 8; ++q) {
            acc[4 * q + 0] += v[q].x * scale;
            acc[4 * q + 1] += v[q].y * scale;
            acc[4 * q + 2] += v[q].z * scale;
            acc[4 * q + 3] += v[q].w * scale;
        }
    }

    const float inv = 1.0f / (float)cnt;
    float* base = w_acc + (size_t)b * NCH * HW + cell;
#pragma unroll
    for (int c = 0; c < NCH; ++c)
        atomicAdd(base + (size_t)c * HW, acc[c] * inv);
    atomicAdd(mask_acc + (size_t)b * HW + cell, (float)cnt);
}

// ---------------------------------------------------------------------------
// Kernel 2: in-place combine with past map.
//   out_w   : holds acc in, final w out        [B][C][HW]
//   out_mask: holds count-sum in, denom out    [B][HW]
// ---------------------------------------------------------------------------
__global__ __launch_bounds__(256) void combine_kernel(
    float*       __restrict__ out_w,
    float*       __restrict__ out_mask,
    const float* __restrict__ past_w,        // [B][C][HW]
    const float* __restrict__ past_mask)     // [B][HW]
{
    const int idx = blockIdx.x * 256 + threadIdx.x;   // over B*HW
    const int b  = idx / HW;
    const int hw = idx - b * HW;

    const float m  = out_mask[idx];
    const float pm = past_mask[idx];
    const float nwm = m + pm;
    const float denom = (nwm == 0.0f) ? 1.0f : nwm;
    const float rdenom = 1.0f / denom;
    const float invT = 1.0f / (float)TFRAMES;

    const size_t base = (size_t)b * NCH * HW + hw;
#pragma unroll
    for (int c = 0; c < NCH; ++c) {
        const size_t a = base + (size_t)c * HW;
        const float nw = out_w[a] * invT;               // new_w
        out_w[a] = (nw * m + past_w[a] * pm) * rdenom;  // final w
    }
    out_mask[idx] = denom;
}

// ---------------------------------------------------------------------------
extern "C" void kernel_launch(void* const* d_in, const int* in_sizes, int n_in,
                              void* d_out, int out_size, void* d_ws, size_t ws_size,
                              hipStream_t stream) {
    (void)in_sizes; (void)n_in; (void)d_ws; (void)ws_size;

    const float* w_part     = (const float*)d_in[0];
    const int*   sorted_idx = (const int*)d_in[1];
    const int*   uniq_list  = (const int*)d_in[2];
    const int*   uniq_cnt   = (const int*)d_in[3];
    const float* past_w     = (const float*)d_in[4];
    const float* past_mask  = (const float*)d_in[5];
    // d_in[6] is T (==TFRAMES), fixed by the reference constants.

    float* out      = (float*)d_out;
    float* out_w    = out;                                // [B][C][HW]
    float* out_mask = out + (size_t)BATCH * NCH * HW;     // [B][HW]

    // d_out doubles as the accumulator: zero it every call (replay-safe).
    hipMemsetAsync(d_out, 0, (size_t)out_size * sizeof(float), stream);

    seg_scatter_kernel<<<BT * SPLIT, 256, 0, stream>>>(
        w_part, sorted_idx, uniq_list, uniq_cnt, out_w, out_mask);

    combine_kernel<<<(BATCH * HW) / 256, 256, 0, stream>>>(
        out_w, out_mask, past_w, past_mask);
}

// Round 2
// 51.276 us; speedup vs baseline: 1.8951x; 1.8951x over previous
//
#include <hip/hip_runtime.h>
#include <climits>

// Problem constants (fixed by the reference's setup_inputs()):
#define BATCH   8
#define TFRAMES 8
#define BT      (BATCH * TFRAMES)   // 64
#define NPTS    1024
#define NCH     32
#define WS      128
#define HW      (WS * WS)           // 16384
#define CELLS   256                 // cells per chunk
#define CHUNKS  (HW / CELLS)        // 64
#define CPAD    33                  // padded channel stride in LDS

// ---------------------------------------------------------------------------
// Kernel 0: per-frame exclusive prefix sum of seq_unique_counts -> starts.
// 64 blocks x 256 threads, int4 per thread, Hillis-Steele over thread totals.
// ---------------------------------------------------------------------------
__global__ __launch_bounds__(256) void scan_kernel(
    const int* __restrict__ uniq_cnt,   // [BT][NPTS]
    int*       __restrict__ starts)     // [BT][NPTS] exclusive prefix
{
    __shared__ int s_tot[256];
    const int tid = threadIdx.x;
    const int bt  = blockIdx.x;

    const int4* cp = reinterpret_cast<const int4*>(uniq_cnt + bt * NPTS);
    int4 c4 = cp[tid];
    const int l0 = c4.x;
    const int l1 = l0 + c4.y;
    const int l2 = l1 + c4.z;
    const int l3 = l2 + c4.w;
    s_tot[tid] = l3;
    __syncthreads();
    for (int off = 1; off < 256; off <<= 1) {
        int v = (tid >= off) ? s_tot[tid - off] : 0;
        __syncthreads();
        s_tot[tid] += v;
        __syncthreads();
    }
    const int ex = (tid > 0) ? s_tot[tid - 1] : 0;
    int4 st;
    st.x = ex;
    st.y = ex + l0;
    st.z = ex + l1;
    st.w = ex + l2;
    reinterpret_cast<int4*>(starts + bt * NPTS)[tid] = st;
}

// first index in [0,NPTS] whose key >= X, where key = (cnt>0 ? list : +inf).
// Valid (cnt>0) prefix of list is sorted ascending; zero-padded tail -> +inf.
__device__ inline int lower_bound_key(const int* __restrict__ list,
                                      const int* __restrict__ cnts, int X)
{
    int lo = 0, hi = NPTS;
    while (lo < hi) {
        const int mid = (lo + hi) >> 1;
        const int k = (cnts[mid] > 0) ? list[mid] : INT_MAX;
        if (k < X) lo = mid + 1; else hi = mid;
    }
    return lo;
}

// ---------------------------------------------------------------------------
// Kernel 1: gather-per-output-tile. Block = (batch b, chunk of 256 cells).
// Accumulate sum-over-T of per-cell segment means into LDS, then fused
// combine with past map; every output element written exactly once.
// ---------------------------------------------------------------------------
__global__ __launch_bounds__(256) void tile_kernel(
    const float* __restrict__ w_part,        // [BT][NPTS][NCH]
    const int*   __restrict__ sorted_idx,    // [BT][NPTS]
    const int*   __restrict__ uniq_list,     // [BT][NPTS]
    const int*   __restrict__ uniq_cnt,      // [BT][NPTS]
    const int*   __restrict__ starts,        // [BT][NPTS]
    const float* __restrict__ past_w,        // [B][C][HW]
    const float* __restrict__ past_mask,     // [B][HW]
    float*       __restrict__ out_w,         // [B][C][HW]
    float*       __restrict__ out_mask)      // [B][HW]
{
    __shared__ float s_acc[CELLS][CPAD];   // [cell][channel], padded stride 33
    __shared__ float s_mask[CELLS];

    const int tid      = threadIdx.x;
    const int b        = blockIdx.x / CHUNKS;
    const int chunk    = blockIdx.x % CHUNKS;
    const int cellBase = chunk * CELLS;

    // zero LDS
#pragma unroll
    for (int k = 0; k < CPAD; ++k) s_acc[tid][k] = 0.0f;
    s_mask[tid] = 0.0f;
    __syncthreads();

    const int slot = tid >> 3;       // 0..31 : entry slot
    const int lane = tid & 7;        // 0..7  : 4 channels each

    for (int t = 0; t < TFRAMES; ++t) {
        const int bt = b * TFRAMES + t;
        const int* lst = uniq_list + bt * NPTS;
        const int* cnts = uniq_cnt + bt * NPTS;
        const int lo = lower_bound_key(lst, cnts, cellBase);
        const int hi = lower_bound_key(lst, cnts, cellBase + CELLS);

        for (int e0 = lo; e0 < hi; e0 += 32) {
            const int e = e0 + slot;
            if (e >= hi) continue;
            const int cell  = lst[e];
            const int cnt   = cnts[e];
            const int start = starts[bt * NPTS + e];

            const int* si = sorted_idx + bt * NPTS;
            float4 lacc = make_float4(0.f, 0.f, 0.f, 0.f);
            for (int p = start; p < start + cnt; ++p) {
                const int j = si[p];
                const float4 v = *reinterpret_cast<const float4*>(
                    w_part + ((size_t)bt * NPTS + j) * NCH + lane * 4);
                float ss = v.x * v.x + v.y * v.y + v.z * v.z + v.w * v.w;
                // reduce sum-of-squares across the 8 lanes of this entry
                ss += __shfl_xor(ss, 1);
                ss += __shfl_xor(ss, 2);
                ss += __shfl_xor(ss, 4);
                const float scale = 1.0f / fmaxf(sqrtf(ss), 1e-12f);
                lacc.x += v.x * scale;
                lacc.y += v.y * scale;
                lacc.z += v.z * scale;
                lacc.w += v.w * scale;
            }
            const float inv = 1.0f / (float)cnt;
            const int cl = cell - cellBase;
            float* ap = &s_acc[cl][lane * 4];
            atomicAdd(ap + 0, lacc.x * inv);
            atomicAdd(ap + 1, lacc.y * inv);
            atomicAdd(ap + 2, lacc.z * inv);
            atomicAdd(ap + 3, lacc.w * inv);
            if (lane == 0) atomicAdd(&s_mask[cl], (float)cnt);
        }
    }
    __syncthreads();

    // ---- fused combine epilogue: thread tid owns cell (cellBase + tid) ----
    const int gcell = cellBase + tid;
    const float m  = s_mask[tid];
    const float pm = past_mask[(size_t)b * HW + gcell];
    const float nwm = m + pm;
    const float denom = (nwm == 0.0f) ? 1.0f : nwm;
    const float r = 1.0f / denom;
    const float invT = 1.0f / (float)TFRAMES;
    out_mask[(size_t)b * HW + gcell] = denom;

#pragma unroll
    for (int c = 0; c < NCH; ++c) {
        const size_t a = ((size_t)b * NCH + c) * HW + gcell;
        const float nw = s_acc[tid][c] * invT;          // new_w
        out_w[a] = (nw * m + past_w[a] * pm) * r;       // final w
    }
}

// ---------------------------------------------------------------------------
extern "C" void kernel_launch(void* const* d_in, const int* in_sizes, int n_in,
                              void* d_out, int out_size, void* d_ws, size_t ws_size,
                              hipStream_t stream) {
    (void)in_sizes; (void)n_in; (void)out_size; (void)ws_size;

    const float* w_part     = (const float*)d_in[0];
    const int*   sorted_idx = (const int*)d_in[1];
    const int*   uniq_list  = (const int*)d_in[2];
    const int*   uniq_cnt   = (const int*)d_in[3];
    const float* past_w     = (const float*)d_in[4];
    const float* past_mask  = (const float*)d_in[5];
    // d_in[6] is T (==TFRAMES), fixed constant.

    float* out      = (float*)d_out;
    float* out_w    = out;                                // [B][C][HW]
    float* out_mask = out + (size_t)BATCH * NCH * HW;     // [B][HW]

    int* starts = (int*)d_ws;                             // [BT][NPTS]

    scan_kernel<<<BT, 256, 0, stream>>>(uniq_cnt, starts);

    tile_kernel<<<BATCH * CHUNKS, 256, 0, stream>>>(
        w_part, sorted_idx, uniq_list, uniq_cnt, starts,
        past_w, past_mask, out_w, out_mask);
}

// Round 3
// 29.711 us; speedup vs baseline: 3.2706x; 1.7258x over previous
//
#include <hip/hip_runtime.h>
#include <climits>

// Problem constants (fixed by the reference's setup_inputs()):
#define BATCH   8
#define TFRAMES 8
#define BT      (BATCH * TFRAMES)   // 64
#define NPTS    1024
#define NCH     32
#define WS      128
#define HW      (WS * WS)           // 16384
#define CELLS   128                 // cells per chunk
#define CHUNKS  (HW / CELLS)        // 128
#define CPAD    33                  // padded channel stride in LDS (4-way max)

// ---------------------------------------------------------------------------
// Kernel 0: per-frame exclusive prefix sum of counts -> starts, AND
// per-chunk entry ranges via LDS-resident binary search (129 boundaries).
// 64 blocks x 256 threads.
// ---------------------------------------------------------------------------
__global__ __launch_bounds__(256) void scan_kernel(
    const int* __restrict__ uniq_cnt,    // [BT][NPTS]
    const int* __restrict__ uniq_list,   // [BT][NPTS]
    int*       __restrict__ starts,      // [BT][NPTS] exclusive prefix
    int*       __restrict__ ranges)      // [BT][CHUNKS+1]
{
    __shared__ int s_tot[256];
    __shared__ int s_key[NPTS];
    const int tid = threadIdx.x;
    const int bt  = blockIdx.x;

    const int4 c4 = reinterpret_cast<const int4*>(uniq_cnt + bt * NPTS)[tid];
    const int4 l4 = reinterpret_cast<const int4*>(uniq_list + bt * NPTS)[tid];
    s_key[tid * 4 + 0] = (c4.x > 0) ? l4.x : INT_MAX;
    s_key[tid * 4 + 1] = (c4.y > 0) ? l4.y : INT_MAX;
    s_key[tid * 4 + 2] = (c4.z > 0) ? l4.z : INT_MAX;
    s_key[tid * 4 + 3] = (c4.w > 0) ? l4.w : INT_MAX;

    const int l0 = c4.x;
    const int l1 = l0 + c4.y;
    const int l2 = l1 + c4.z;
    const int l3 = l2 + c4.w;
    s_tot[tid] = l3;
    __syncthreads();
    for (int off = 1; off < 256; off <<= 1) {
        int v = (tid >= off) ? s_tot[tid - off] : 0;
        __syncthreads();
        s_tot[tid] += v;
        __syncthreads();
    }
    const int ex = (tid > 0) ? s_tot[tid - 1] : 0;
    int4 st;
    st.x = ex;
    st.y = ex + l0;
    st.z = ex + l1;
    st.w = ex + l2;
    reinterpret_cast<int4*>(starts + bt * NPTS)[tid] = st;

    // 129 per-chunk boundary searches over LDS keys
    if (tid <= CHUNKS) {
        const int X = tid * CELLS;
        int lo = 0, hi = NPTS;
        while (lo < hi) {
            const int mid = (lo + hi) >> 1;
            if (s_key[mid] < X) lo = mid + 1; else hi = mid;
        }
        ranges[bt * (CHUNKS + 1) + tid] = lo;
    }
}

// ---------------------------------------------------------------------------
// Kernel 1: gather-per-output-tile + fused combine.
// Block = (batch b, chunk of 128 cells); 4 waves each handle 2 frames.
// ---------------------------------------------------------------------------
__global__ __launch_bounds__(256) void tile_kernel(
    const float* __restrict__ w_part,        // [BT][NPTS][NCH]
    const int*   __restrict__ sorted_idx,    // [BT][NPTS]
    const int*   __restrict__ uniq_list,     // [BT][NPTS]
    const int*   __restrict__ uniq_cnt,      // [BT][NPTS]
    const int*   __restrict__ starts,        // [BT][NPTS]
    const int*   __restrict__ ranges,        // [BT][CHUNKS+1]
    const float* __restrict__ past_w,        // [B][C][HW]
    const float* __restrict__ past_mask,     // [B][HW]
    float*       __restrict__ out_w,         // [B][C][HW]
    float*       __restrict__ out_mask)      // [B][HW]
{
    __shared__ float s_acc[CELLS][CPAD];
    __shared__ float s_mask[CELLS];

    const int tid      = threadIdx.x;
    const int b        = blockIdx.x / CHUNKS;
    const int chunk    = blockIdx.x % CHUNKS;
    const int cellBase = chunk * CELLS;

    // zero LDS
    float* flat = &s_acc[0][0];
    for (int i = tid; i < CELLS * CPAD; i += 256) flat[i] = 0.0f;
    if (tid < CELLS) s_mask[tid] = 0.0f;
    __syncthreads();

    const int wave  = tid >> 6;      // 0..3
    const int lane  = tid & 63;
    const int slot  = lane >> 3;     // 0..7 entry slot within wave
    const int lane8 = lane & 7;      // 4 channels each

    for (int tt = 0; tt < 2; ++tt) {
        const int t  = wave * 2 + tt;
        const int bt = b * TFRAMES + t;
        const int lo = ranges[bt * (CHUNKS + 1) + chunk];
        const int hi = ranges[bt * (CHUNKS + 1) + chunk + 1];
        const int* __restrict__ lst  = uniq_list + bt * NPTS;
        const int* __restrict__ cnts = uniq_cnt + bt * NPTS;
        const int* __restrict__ stp  = starts + bt * NPTS;
        const int* __restrict__ si   = sorted_idx + bt * NPTS;

        for (int e0 = lo; e0 < hi; e0 += 8) {
            const int e = e0 + slot;
            if (e < hi) {
                const int cell  = lst[e];
                const int cnt   = cnts[e];
                const int start = stp[e];
                float4 lacc = make_float4(0.f, 0.f, 0.f, 0.f);
                for (int p = start; p < start + cnt; ++p) {
                    const int j = si[p];
                    const float4 v = *reinterpret_cast<const float4*>(
                        w_part + ((size_t)bt * NPTS + j) * NCH + lane8 * 4);
                    float ss = v.x * v.x + v.y * v.y + v.z * v.z + v.w * v.w;
                    ss += __shfl_xor(ss, 1);
                    ss += __shfl_xor(ss, 2);
                    ss += __shfl_xor(ss, 4);
                    const float scale = 1.0f / fmaxf(sqrtf(ss), 1e-12f);
                    lacc.x += v.x * scale;
                    lacc.y += v.y * scale;
                    lacc.z += v.z * scale;
                    lacc.w += v.w * scale;
                }
                const float invc = 1.0f / (float)cnt;
                const int cl = cell - cellBase;
                float* ap = &s_acc[cl][lane8 * 4];
                atomicAdd(ap + 0, lacc.x * invc);
                atomicAdd(ap + 1, lacc.y * invc);
                atomicAdd(ap + 2, lacc.z * invc);
                atomicAdd(ap + 3, lacc.w * invc);
                if (lane8 == 0) atomicAdd(&s_mask[cl], (float)cnt);
            }
        }
    }
    __syncthreads();

    // ---- fused combine epilogue, float4-vectorized over cells ----
    // thread -> (4 channels = (tid>>5)*4.., 4 cells = (tid&31)*4..)
    const int cellq = tid & 31;
    const int cgrp  = tid >> 5;
    const int c0    = cgrp * 4;
    const int gc    = cellBase + cellq * 4;
    const float invT = 1.0f / (float)TFRAMES;

    const float4 pm4 = *reinterpret_cast<const float4*>(past_mask + (size_t)b * HW + gc);
    float m[4], pm[4], r[4], dn[4];
    pm[0] = pm4.x; pm[1] = pm4.y; pm[2] = pm4.z; pm[3] = pm4.w;
#pragma unroll
    for (int i = 0; i < 4; ++i) {
        m[i] = s_mask[cellq * 4 + i];
        const float nwm = m[i] + pm[i];
        dn[i] = (nwm == 0.0f) ? 1.0f : nwm;
        r[i] = 1.0f / dn[i];
    }
    if (cgrp == 0) {
        float4 d4 = make_float4(dn[0], dn[1], dn[2], dn[3]);
        *reinterpret_cast<float4*>(out_mask + (size_t)b * HW + gc) = d4;
    }

#pragma unroll
    for (int k = 0; k < 4; ++k) {
        const int c = c0 + k;
        const size_t a = ((size_t)b * NCH + c) * HW + gc;
        const float4 pw = *reinterpret_cast<const float4*>(past_w + a);
        float4 o;
        o.x = (s_acc[cellq * 4 + 0][c] * invT * m[0] + pw.x * pm[0]) * r[0];
        o.y = (s_acc[cellq * 4 + 1][c] * invT * m[1] + pw.y * pm[1]) * r[1];
        o.z = (s_acc[cellq * 4 + 2][c] * invT * m[2] + pw.z * pm[2]) * r[2];
        o.w = (s_acc[cellq * 4 + 3][c] * invT * m[3] + pw.w * pm[3]) * r[3];
        *reinterpret_cast<float4*>(out_w + a) = o;
    }
}

// ---------------------------------------------------------------------------
extern "C" void kernel_launch(void* const* d_in, const int* in_sizes, int n_in,
                              void* d_out, int out_size, void* d_ws, size_t ws_size,
                              hipStream_t stream) {
    (void)in_sizes; (void)n_in; (void)out_size; (void)ws_size;

    const float* w_part     = (const float*)d_in[0];
    const int*   sorted_idx = (const int*)d_in[1];
    const int*   uniq_list  = (const int*)d_in[2];
    const int*   uniq_cnt   = (const int*)d_in[3];
    const float* past_w     = (const float*)d_in[4];
    const float* past_mask  = (const float*)d_in[5];
    // d_in[6] is T (==TFRAMES), fixed constant.

    float* out      = (float*)d_out;
    float* out_w    = out;                                // [B][C][HW]
    float* out_mask = out + (size_t)BATCH * NCH * HW;     // [B][HW]

    int* starts = (int*)d_ws;                             // [BT][NPTS]
    int* ranges = starts + (size_t)BT * NPTS;             // [BT][CHUNKS+1]

    scan_kernel<<<BT, 256, 0, stream>>>(uniq_cnt, uniq_list, starts, ranges);

    tile_kernel<<<BATCH * CHUNKS, 256, 0, stream>>>(
        w_part, sorted_idx, uniq_list, uniq_cnt, starts, ranges,
        past_w, past_mask, out_w, out_mask);
}